// Round 8
// baseline (12.849 us; speedup 1.0000x reference)
//
#include <hip/hip_runtime.h>
#include <hip/hip_bf16.h>
#include <math.h>

// recon: [B=4, N=64, D=3] f32, gt: [B=4, M=2048, D=3] f32
// P = 2016 tril pairs (i>j); 5 interp pts f in {0,.25,.5,.75,1}; out [B,P].
//
// d_t/2 = w_t + const(pair,t),  w_t = (1-f)*A + f*Ds = A + f*(Ds-A)
//   gn = -g, hh = 0.5||g||^2 (LDS);  A = e.gn+hh (j only), Ds = s.gn+hh (i only)
// r_t = min_g w_t;  out = 0.4*sum_t r_t + ||e||^2 + e.u + 0.375||u||^2.
//
// Geometry: 252 blocks x 1024 thr = 4032 waves = 4 waves/SIMD (issue-
// saturating; R5 showed 2/SIMD costs 1.65x). Wave owns 2 consecutive pairs;
// ~97% share row i -> shared Ds dot + shared t=4 min chain.
// R8: DPP wave-min (ctrl as template constant) + 1-pass vectorized staging.
#define BATCH 4
#define NPTS 64
#define MGT 2048
#define NPAIR 2016
#define PPW 2
#define THREADS 1024
#define WAVES_PER_BLOCK 16
#define CHUNKS_PER_BLOCK 16
#define BLOCKS_PER_BATCH 63

#define FLT_BIG 3.4e38f

// One DPP-min step; CTRL must be a compile-time constant.
// update_dpp(old=+inf, src, CTRL, 0xf, 0xf, false): lanes with no source
// get +inf (min identity).
template <int CTRL>
__device__ __forceinline__ float dpp_min_step(float x) {
    const int r = __builtin_amdgcn_update_dpp(__float_as_int(FLT_BIG),
                                              __float_as_int(x),
                                              CTRL, 0xf, 0xf, false);
    return fminf(x, __int_as_float(r));
}
// Full-wave (64-lane) min; result valid in lane 63.
// row_shr 1,2,4,8 -> lane15 of each 16-lane row holds row min;
// row_bcast15 (0x142) folds rows 0->1, 2->3; row_bcast31 (0x143) folds
// halves -> lane 63.
__device__ __forceinline__ float wave_min63(float x) {
    x = dpp_min_step<0x111>(x);  // row_shr:1
    x = dpp_min_step<0x112>(x);  // row_shr:2
    x = dpp_min_step<0x114>(x);  // row_shr:4
    x = dpp_min_step<0x118>(x);  // row_shr:8
    x = dpp_min_step<0x142>(x);  // row_bcast:15
    x = dpp_min_step<0x143>(x);  // row_bcast:31
    return x;                    // lane 63 holds the wave min
}

__global__ __launch_bounds__(THREADS)
void edge_cdis_kernel(const float* __restrict__ recon,
                      const float* __restrict__ gt,
                      float* __restrict__ out) {
    __shared__ float4 gts4[MGT];   // {-gx,-gy,-gz, 0.5||g||^2}, 32 KB

    const int tid  = threadIdx.x;
    const int wib  = tid >> 6;
    const int lane = tid & 63;

    const int b  = blockIdx.x / BLOCKS_PER_BATCH;
    const int cb = (blockIdx.x % BLOCKS_PER_BATCH) * CHUNKS_PER_BLOCK + wib;

    // ---- Stage gt[b] -> LDS, one pass: thread t loads points 2t, 2t+1
    // (24 contiguous bytes = 3x float2, fully coalesced) ----
    {
        const float2* __restrict__ g2 =
            (const float2*)(gt + b * (MGT * 3));
        const float2 A0 = g2[3 * tid + 0];
        const float2 A1 = g2[3 * tid + 1];
        const float2 A2 = g2[3 * tid + 2];
        float4 v0, v1;
        v0.x = -A0.x; v0.y = -A0.y; v0.z = -A1.x;
        v0.w = 0.5f * fmaf(A1.x, A1.x, fmaf(A0.y, A0.y, A0.x * A0.x));
        v1.x = -A1.y; v1.y = -A2.x; v1.z = -A2.y;
        v1.w = 0.5f * fmaf(A2.y, A2.y, fmaf(A2.x, A2.x, A1.y * A1.y));
        gts4[2 * tid + 0] = v0;
        gts4[2 * tid + 1] = v1;
    }

    // ---- Setup (independent of LDS, overlaps staging) ----
    const int p0 = 2 * cb;
    int i0 = (int)((1.0f + sqrtf(1.0f + 8.0f * (float)p0)) * 0.5f);
    while (i0 * (i0 - 1) / 2 > p0) --i0;
    while ((i0 + 1) * i0 / 2 <= p0) ++i0;
    const int j0 = p0 - i0 * (i0 - 1) / 2;
    const bool same_row = (j0 + 1 < i0);
    const int i1 = same_row ? i0 : (i0 + 1);
    const int j1 = same_row ? (j0 + 1) : 0;

    const float* __restrict__ rb = recon + b * (NPTS * 3);
    int i_[PPW] = {i0, i1}, j_[PPW] = {j0, j1};
    float ex[PPW], ey[PPW], ez[PPW];
    float sx[PPW], sy[PPW], sz[PPW];
    float cadd[PPW];
    #pragma unroll
    for (int k = 0; k < PPW; ++k) {
        sx[k] = rb[i_[k] * 3 + 0]; sy[k] = rb[i_[k] * 3 + 1]; sz[k] = rb[i_[k] * 3 + 2];
        ex[k] = rb[j_[k] * 3 + 0]; ey[k] = rb[j_[k] * 3 + 1]; ez[k] = rb[j_[k] * 3 + 2];
        const float ux = sx[k] - ex[k], uy = sy[k] - ey[k], uz = sz[k] - ez[k];
        const float e2 = ex[k]*ex[k] + ey[k]*ey[k] + ez[k]*ez[k];
        const float eu = ex[k]*ux + ey[k]*uy + ez[k]*uz;
        const float c  = ux*ux + uy*uy + uz*uz;
        cadd[k] = e2 + eu + 0.375f * c;
    }

    __syncthreads();

    float r[PPW][5];
    #pragma unroll
    for (int k = 0; k < PPW; ++k)
        #pragma unroll
        for (int t = 0; t < 5; ++t) r[k][t] = FLT_BIG;
    float r4s = FLT_BIG;

    if (same_row) {
        const float Sx = sx[0], Sy = sy[0], Sz = sz[0];
        #pragma unroll 16
        for (int g = lane; g < MGT; g += 64) {
            const float4 gv = gts4[g];
            float Ds = fmaf(Sx, gv.x, gv.w);
            Ds = fmaf(Sy, gv.y, Ds);
            Ds = fmaf(Sz, gv.z, Ds);
            r4s = fminf(r4s, Ds);
            #pragma unroll
            for (int k = 0; k < PPW; ++k) {
                float A = fmaf(ex[k], gv.x, gv.w);
                A = fmaf(ey[k], gv.y, A);
                A = fmaf(ez[k], gv.z, A);
                const float G = Ds - A;
                r[k][0] = fminf(r[k][0], A);
                r[k][1] = fminf(r[k][1], fmaf(0.25f, G, A));
                r[k][2] = fminf(r[k][2], fmaf(0.50f, G, A));
                r[k][3] = fminf(r[k][3], fmaf(0.75f, G, A));
            }
        }
    } else {
        #pragma unroll 16
        for (int g = lane; g < MGT; g += 64) {
            const float4 gv = gts4[g];
            #pragma unroll
            for (int k = 0; k < PPW; ++k) {
                float A = fmaf(ex[k], gv.x, gv.w);
                A = fmaf(ey[k], gv.y, A);
                A = fmaf(ez[k], gv.z, A);
                float Ds = fmaf(sx[k], gv.x, gv.w);
                Ds = fmaf(sy[k], gv.y, Ds);
                Ds = fmaf(sz[k], gv.z, Ds);
                const float G = Ds - A;
                r[k][0] = fminf(r[k][0], A);
                r[k][1] = fminf(r[k][1], fmaf(0.25f, G, A));
                r[k][2] = fminf(r[k][2], fmaf(0.50f, G, A));
                r[k][3] = fminf(r[k][3], fmaf(0.75f, G, A));
                r[k][4] = fminf(r[k][4], Ds);
            }
        }
    }

    // ---- Wave-wide min via DPP (result in lane 63) ----
    #pragma unroll
    for (int k = 0; k < PPW; ++k)
        #pragma unroll
        for (int t = 0; t < 4; ++t)
            r[k][t] = wave_min63(r[k][t]);
    if (same_row) {
        r4s = wave_min63(r4s);
    } else {
        #pragma unroll
        for (int k = 0; k < PPW; ++k)
            r[k][4] = wave_min63(r[k][4]);
    }

    if (lane == 63) {
        #pragma unroll
        for (int k = 0; k < PPW; ++k) {
            const float r4 = same_row ? r4s : r[k][4];
            const float sr = r[k][0] + r[k][1] + r[k][2] + r[k][3] + r4;
            out[b * NPAIR + p0 + k] = 0.4f * sr + cadd[k];
        }
    }
}

extern "C" void kernel_launch(void* const* d_in, const int* in_sizes, int n_in,
                              void* d_out, int out_size, void* d_ws, size_t ws_size,
                              hipStream_t stream) {
    const float* recon = (const float*)d_in[0];
    const float* gt    = (const float*)d_in[1];
    float* out = (float*)d_out;

    const int blocks = BATCH * BLOCKS_PER_BATCH;  // 252
    edge_cdis_kernel<<<blocks, THREADS, 0, stream>>>(recon, gt, out);
}